// Round 12
// baseline (1663.704 us; speedup 1.0000x reference)
//
#include <hip/hip_runtime.h>
#include <hip/hip_bf16.h>
#include <stdint.h>

// DIORA inside pass. B=128, T=32, D=400, ncells=528.
// Per-cell transform caching via bf16 MFMA GEMM into interleaved planes:
//   LP[cell][2j+0]=a_j (h@u_lh), LP[cell][2j+1]=e_j (c@u_lc)
//   RP[cell][2j+0]=b2_j (h@u_rh), RP[cell][2j+1]=f_j (c@u_rc)
//   G [cell][j]   =g_j (h@w_score)
// NEW: 8 independent group-pipelines (16 b's / 64 blocks each, coop-launched,
// 512 blocks co-resident). Each group loops all 31 levels internally with a
// 64-block device-scope barrier (atomic release/acquire + s_sleep spin) —
// groups share NOTHING, so no grid-wide sync (R7 measured grid.sync ~140us).
// Fallback on occupancy/launch failure: the R11-verified multi-launch path.

#define BB 128
#define TT 32
#define DD 400
#define NCELLS 528
#define NW 2000   // 5 weight blocks x 400 output cols
#define KP 416    // K padded to 13*32

typedef __attribute__((ext_vector_type(8))) short s8v;
typedef __attribute__((ext_vector_type(4))) float f32x4;

__device__ __forceinline__ int offs_of(int v) { return v * TT - (v * (v - 1)) / 2; }

__device__ __forceinline__ float asf(uint32_t bits) {
    union { uint32_t i; float f; } v; v.i = bits; return v.f;
}
__device__ __forceinline__ uint16_t f2bf(float f) {
    union { float f; uint32_t i; } v; v.f = f;
    uint32_t x = v.i;
    return (uint16_t)((x + 0x7fffu + ((x >> 16) & 1u)) >> 16);  // RNE
}
// Fast tanh: 1 - 2/(exp2(2*log2e*x)+1). ~1e-6 abs error.
__device__ __forceinline__ float tanh_fast(float x) {
    float e = __builtin_amdgcn_exp2f(x * 2.8853900817779268f);
    return 1.f - 2.f * __builtin_amdgcn_rcpf(e + 1.f);
}

__device__ __forceinline__ void block_reduce2(float& a, float& b, float* sred) {
#pragma unroll
    for (int o = 32; o > 0; o >>= 1) { a += __shfl_down(a, o); b += __shfl_down(b, o); }
    int lane = threadIdx.x & 63, w = threadIdx.x >> 6;
    if (lane == 0) { sred[w] = a; sred[4 + w] = b; }
    __syncthreads();
    a = sred[0] + sred[1] + sred[2] + sred[3];
    b = sred[4] + sred[5] + sred[6] + sred[7];
    __syncthreads();
}

// 64-block group barrier. Release makes prior writes agent-visible; acquire
// invalidates stale caches. Fresh counter per use (no wraparound).
__device__ __forceinline__ void group_barrier(uint32_t* cnt) {
    __syncthreads();
    if (threadIdx.x == 0) {
        __hip_atomic_fetch_add(cnt, 1u, __ATOMIC_RELEASE, __HIP_MEMORY_SCOPE_AGENT);
        while (__hip_atomic_load(cnt, __ATOMIC_ACQUIRE, __HIP_MEMORY_SCOPE_AGENT) < 64u)
            __builtin_amdgcn_s_sleep(2);
    }
    __syncthreads();
}

// ---------------- pack (+ barrier-counter zeroing) ----------------
__global__ void pack_k(const float* __restrict__ u_lh, const float* __restrict__ u_rh,
                       const float* __restrict__ w_score, const float* __restrict__ u_lc,
                       const float* __restrict__ u_rc, const float* __restrict__ w_leaf_h,
                       const float* __restrict__ w_leaf_c, const float* __restrict__ x,
                       uint16_t* __restrict__ WT, uint16_t* __restrict__ WLT,
                       uint16_t* __restrict__ XB, uint32_t* __restrict__ CNT) {
    int idx = blockIdx.x * blockDim.x + threadIdx.x;
    const int nWT = NW * KP, nWLT = 800 * KP, nXB = 4096 * KP;
    if (idx < nWT) {
        int n = idx / KP, k = idx - n * KP;
        float v = 0.f;
        if (k < DD) {
            const float* src = (n < 400) ? u_lh : (n < 800) ? u_rh : (n < 1200) ? w_score
                               : (n < 1600) ? u_lc : u_rc;
            v = src[k * DD + (n % 400)];
        }
        WT[idx] = f2bf(v);
    } else if (idx < nWT + nWLT) {
        int q = idx - nWT; int n = q / KP, k = q - n * KP;
        float v = 0.f;
        if (k < DD) v = (n < 400) ? w_leaf_h[k * DD + n] : w_leaf_c[k * DD + (n - 400)];
        WLT[q] = f2bf(v);
    } else if (idx < nWT + nWLT + nXB) {
        int q = idx - nWT - nWLT; int r = q / KP, k = q - r * KP;
        XB[q] = f2bf(k < DD ? x[(size_t)r * DD + k] : 0.f);
    } else if (idx < nWT + nWLT + nXB + 512) {
        CNT[idx - nWT - nWLT - nXB] = 0u;
    }
}

// ---------------- leaf pre-activation GEMM (verified; LDS-staged) ----------
__global__ __launch_bounds__(256)
void tgemm_k(const uint16_t* __restrict__ XB, const uint16_t* __restrict__ WLT,
             float* __restrict__ PREout) {
    __shared__ short As[256][40];
    __shared__ short Ws[80][40];
    const int t = threadIdx.x, lane = t & 63, w = t >> 6;
    const int n0 = blockIdx.x * 80;
    const int tile_m = blockIdx.y * 256;

    const int arow_l = t >> 2, asub = t & 3;
    const uint16_t* aptr[4];
#pragma unroll
    for (int p = 0; p < 4; p++) {
        int gr = tile_m + arow_l + 64 * p;
        aptr[p] = XB + (size_t)gr * KP + asub * 8;
    }
    const uint16_t* wptr0 = WLT + (size_t)(n0 + (t >> 2)) * KP + (t & 3) * 8;
    const uint16_t* wptr1 = WLT + (size_t)(n0 + 64 + (t >> 2)) * KP + (t & 3) * 8;

    const int frow = lane & 15, kcol = (lane >> 4) * 8;
    f32x4 acc[4][5];
#pragma unroll
    for (int mi = 0; mi < 4; mi++)
#pragma unroll
        for (int ni = 0; ni < 5; ni++) acc[mi][ni] = (f32x4)(0.f);

    for (int k0 = 0; k0 < KP; k0 += 32) {
        s8v av[4];
#pragma unroll
        for (int p = 0; p < 4; p++) av[p] = *(const s8v*)(aptr[p] + k0);
        s8v wv0 = *(const s8v*)(wptr0 + k0);
        s8v wv1;
        if (t < 64) wv1 = *(const s8v*)(wptr1 + k0);
        __syncthreads();
#pragma unroll
        for (int p = 0; p < 4; p++) *(s8v*)&As[arow_l + 64 * p][asub * 8] = av[p];
        *(s8v*)&Ws[t >> 2][(t & 3) * 8] = wv0;
        if (t < 64) *(s8v*)&Ws[64 + (t >> 2)][(t & 3) * 8] = wv1;
        __syncthreads();
        s8v a[4];
#pragma unroll
        for (int mi = 0; mi < 4; mi++)
            a[mi] = *(const s8v*)&As[64 * w + 16 * mi + frow][kcol];
#pragma unroll
        for (int ni = 0; ni < 5; ni++) {
            s8v bv = *(const s8v*)&Ws[16 * ni + frow][kcol];
#pragma unroll
            for (int mi = 0; mi < 4; mi++)
                acc[mi][ni] = __builtin_amdgcn_mfma_f32_16x16x32_bf16(a[mi], bv, acc[mi][ni], 0, 0, 0);
        }
    }
#pragma unroll
    for (int mi = 0; mi < 4; mi++) {
        int rbase = tile_m + 64 * w + 16 * mi + 4 * (lane >> 4);
#pragma unroll
        for (int i = 0; i < 4; i++) {
            int gr = rbase + i;
            float* o = PREout + (size_t)gr * 800 + n0 + frow;
#pragma unroll
            for (int ni = 0; ni < 5; ni++) o[16 * ni] = acc[mi][ni][i];
        }
    }
}

// ---------------- paired transform GEMM tile (R8-verified body + row guard) --
// kind: 0 = LP pair (u_lh+u_lc), 1 = RP pair (u_rh+u_rc), 2 = G (w_score).
// Rows gr in [0,Mtot): rb = gr/Lq (b offset from b_base), ri = gr%Lq.
__device__ __forceinline__
void tpgemm_tile(const uint16_t* __restrict__ HB, const uint16_t* __restrict__ CB,
                 const uint16_t* __restrict__ WT,
                 uint16_t* __restrict__ LP, uint16_t* __restrict__ RP,
                 uint16_t* __restrict__ G,
                 int Lq, int cellbase, int b_base, int nch, int kind,
                 int tile_m, int Mtot,
                 short (*AsH)[40], short (*AsC)[40],
                 short (*WsH)[40], short (*WsC)[40]) {
    const int t = threadIdx.x, lane = t & 63, w = t >> 6;
    const int n0 = nch * 80;
    const bool doC = (kind != 2);

    const int wh0 = (kind == 0) ? n0 : (kind == 1) ? 400 + n0 : 800 + n0;
    const int wc0 = (kind == 0) ? 1200 + n0 : 1600 + n0;  // unused for kind==2

    const int arow_l = t >> 2, asub = t & 3;
    const uint16_t *aptrH[2], *aptrC[2];
#pragma unroll
    for (int p = 0; p < 2; p++) {
        int gr = tile_m + arow_l + 64 * p;
        if (gr >= Mtot) gr = 0;  // guarded row: safe dummy read
        int rb = gr / Lq, ri = gr - rb * Lq;
        aptrH[p] = HB + (size_t)((b_base + rb) * NCELLS + cellbase + ri) * DD + asub * 8;
        aptrC[p] = CB + (size_t)((b_base + rb) * 32 + ri) * DD + asub * 8;
    }
    const uint16_t* wptrH0 = WT + (size_t)(wh0 + (t >> 2)) * KP + (t & 3) * 8;
    const uint16_t* wptrH1 = WT + (size_t)(wh0 + 64 + (t >> 2)) * KP + (t & 3) * 8;
    const uint16_t* wptrC0 = WT + (size_t)(wc0 + (t >> 2)) * KP + (t & 3) * 8;
    const uint16_t* wptrC1 = WT + (size_t)(wc0 + 64 + (t >> 2)) * KP + (t & 3) * 8;

    const int frow = lane & 15, kcol = (lane >> 4) * 8;
    f32x4 accH[2][5], accC[2][5];
#pragma unroll
    for (int mi = 0; mi < 2; mi++)
#pragma unroll
        for (int ni = 0; ni < 5; ni++) { accH[mi][ni] = (f32x4)(0.f); accC[mi][ni] = (f32x4)(0.f); }

    for (int k0 = 0; k0 < KP; k0 += 32) {
        s8v avH0 = *(const s8v*)(aptrH[0] + k0);
        s8v avH1 = *(const s8v*)(aptrH[1] + k0);
        s8v wvH0 = *(const s8v*)(wptrH0 + k0);
        s8v wvH1;
        if (t < 64) wvH1 = *(const s8v*)(wptrH1 + k0);
        s8v avC0, avC1, wvC0, wvC1;
        if (doC) {
            avC0 = *(const s8v*)(aptrC[0] + k0);
            avC1 = *(const s8v*)(aptrC[1] + k0);
            wvC0 = *(const s8v*)(wptrC0 + k0);
            if (t < 64) wvC1 = *(const s8v*)(wptrC1 + k0);
        }
        __syncthreads();
        *(s8v*)&AsH[arow_l][asub * 8] = avH0;
        *(s8v*)&AsH[arow_l + 64][asub * 8] = avH1;
        *(s8v*)&WsH[t >> 2][(t & 3) * 8] = wvH0;
        if (t < 64) *(s8v*)&WsH[64 + (t >> 2)][(t & 3) * 8] = wvH1;
        if (doC) {
            *(s8v*)&AsC[arow_l][asub * 8] = avC0;
            *(s8v*)&AsC[arow_l + 64][asub * 8] = avC1;
            *(s8v*)&WsC[t >> 2][(t & 3) * 8] = wvC0;
            if (t < 64) *(s8v*)&WsC[64 + (t >> 2)][(t & 3) * 8] = wvC1;
        }
        __syncthreads();
        s8v aH0 = *(const s8v*)&AsH[32 * w + frow][kcol];
        s8v aH1 = *(const s8v*)&AsH[32 * w + 16 + frow][kcol];
        s8v aC0, aC1;
        if (doC) {
            aC0 = *(const s8v*)&AsC[32 * w + frow][kcol];
            aC1 = *(const s8v*)&AsC[32 * w + 16 + frow][kcol];
        }
#pragma unroll
        for (int ni = 0; ni < 5; ni++) {
            s8v bvH = *(const s8v*)&WsH[16 * ni + frow][kcol];
            accH[0][ni] = __builtin_amdgcn_mfma_f32_16x16x32_bf16(aH0, bvH, accH[0][ni], 0, 0, 0);
            accH[1][ni] = __builtin_amdgcn_mfma_f32_16x16x32_bf16(aH1, bvH, accH[1][ni], 0, 0, 0);
            if (doC) {
                s8v bvC = *(const s8v*)&WsC[16 * ni + frow][kcol];
                accC[0][ni] = __builtin_amdgcn_mfma_f32_16x16x32_bf16(aC0, bvC, accC[0][ni], 0, 0, 0);
                accC[1][ni] = __builtin_amdgcn_mfma_f32_16x16x32_bf16(aC1, bvC, accC[1][ni], 0, 0, 0);
            }
        }
    }

    if (kind == 2) {
#pragma unroll
        for (int mi = 0; mi < 2; mi++) {
            int rbase = tile_m + 32 * w + 16 * mi + 4 * (lane >> 4);
#pragma unroll
            for (int i = 0; i < 4; i++) {
                int gr = rbase + i;
                if (gr >= Mtot) continue;
                int rb = gr / Lq, ri = gr - rb * Lq;
                size_t row = (size_t)((b_base + rb) * NCELLS + cellbase + ri);
                uint16_t* o = G + row * 400 + n0 + frow;
#pragma unroll
                for (int ni = 0; ni < 5; ni++) o[16 * ni] = f2bf(accH[mi][ni][i]);
            }
        }
    } else {
        uint16_t* tb = (kind == 0) ? LP : RP;
#pragma unroll
        for (int mi = 0; mi < 2; mi++) {
            int rbase = tile_m + 32 * w + 16 * mi + 4 * (lane >> 4);
#pragma unroll
            for (int i = 0; i < 4; i++) {
                int gr = rbase + i;
                if (gr >= Mtot) continue;
                int rb = gr / Lq, ri = gr - rb * Lq;
                size_t row = (size_t)((b_base + rb) * NCELLS + cellbase + ri);
                uint32_t* o = (uint32_t*)(tb + row * 800) + n0 + frow;
#pragma unroll
                for (int ni = 0; ni < 5; ni++)
                    o[16 * ni] = (uint32_t)f2bf(accH[mi][ni][i])
                               | ((uint32_t)f2bf(accC[mi][ni][i]) << 16);
            }
        }
    }
}

// Standalone wrapper (leaf transforms + fallback): identical mapping to R11.
__global__ __launch_bounds__(256)
void tpgemm_k(const uint16_t* __restrict__ HB, const uint16_t* __restrict__ CB,
              const uint16_t* __restrict__ WT,
              uint16_t* __restrict__ LP, uint16_t* __restrict__ RP,
              uint16_t* __restrict__ G, int Lcur, int cellbase) {
    __shared__ short AsH[128][40], AsC[128][40], WsH[80][40], WsC[80][40];
    tpgemm_tile(HB, CB, WT, LP, RP, G, Lcur, cellbase, 0,
                blockIdx.x % 5, blockIdx.x / 5, blockIdx.y * 128, 128 * Lcur,
                AsH, AsC, WsH, WsC);
}

// ---------------- leaf epilogue ----------------
__global__ __launch_bounds__(256)
void leaf_norm_k(const float* __restrict__ PRE, const float* __restrict__ blh,
                 const float* __restrict__ blc, float* __restrict__ Hchart,
                 uint16_t* __restrict__ HB, uint16_t* __restrict__ CB,
                 float* __restrict__ cs) {
    const int r = blockIdx.x;  // b*32 + t
    const int b = r >> 5, tt = r & 31;
    const int t = threadIdx.x;
    const int d = t * 2;
    float th0 = 0, th1 = 0, tc0 = 0, tc1 = 0;
    if (d < DD) {
        const float* p = PRE + (size_t)r * 800;
        th0 = tanh_fast(p[d] + blh[d]);
        th1 = tanh_fast(p[d + 1] + blh[d + 1]);
        tc0 = tanh_fast(p[400 + d] + blc[d]);
        tc1 = tanh_fast(p[400 + d + 1] + blc[d + 1]);
    }
    __shared__ float sred[8];
    float nh = th0 * th0 + th1 * th1, nc = tc0 * tc0 + tc1 * tc1;
    block_reduce2(nh, nc, sred);
    float rh = 1.f / fmaxf(sqrtf(nh), 1e-8f);
    float rc = 1.f / fmaxf(sqrtf(nc), 1e-8f);
    if (d < DD) {
        size_t ho = (size_t)(b * NCELLS + tt) * DD + d;
        float h0 = th0 * rh, h1 = th1 * rh, c0 = tc0 * rc, c1 = tc1 * rc;
        Hchart[ho] = h0; Hchart[ho + 1] = h1;
        *(uint32_t*)(HB + ho) = (uint32_t)f2bf(h0) | ((uint32_t)f2bf(h1) << 16);
        *(uint32_t*)(CB + (size_t)(b * 32 + tt) * DD + d) =
            (uint32_t)f2bf(c0) | ((uint32_t)f2bf(c1) << 16);
    }
    if (t == 0) cs[b * NCELLS + tt] = 0.f;
}

// ---------------- per-cell body (R11-verified level_k internals) ----------
__device__ void level_cell(float* __restrict__ Hchart, uint16_t* __restrict__ HB,
                           uint16_t* __restrict__ CB, float* __restrict__ cs,
                           const uint16_t* __restrict__ LP, const uint16_t* __restrict__ RP,
                           const uint16_t* __restrict__ G,
                           const float* __restrict__ b_h, const float* __restrict__ b_c,
                           int level, int b, int i,
                           float* sh_s, float* sh_p, float* sred) {
    const int N = level;
    const int cell = offs_of(level) + i;
    const int t = threadIdx.x, lane = t & 63, w = t >> 6;
    __syncthreads();  // shared-array reuse guard across sequential cells

    for (int k = w; k < N; k += 4) {
        int lcell = offs_of(k) + i;
        int rcell = offs_of(level - k - 1) + i + k + 1;
        const uint32_t* g = (const uint32_t*)(G + (size_t)(b * NCELLS + lcell) * DD);
        const uint32_t* hr = (const uint32_t*)(HB + (size_t)(b * NCELLS + rcell) * DD);
        float s = 0.f;
        for (int d2 = lane; d2 < 200; d2 += 64) {
            uint32_t gv = g[d2], hv = hr[d2];
            s += asf(gv << 16) * asf(hv << 16)
               + asf(gv & 0xffff0000u) * asf(hv & 0xffff0000u);
        }
#pragma unroll
        for (int o = 32; o > 0; o >>= 1) s += __shfl_down(s, o);
        if (lane == 0) sh_s[k] = s + cs[b * NCELLS + lcell] + cs[b * NCELLS + rcell];
    }
    __syncthreads();

    if (t == 0) {
        float m = -1e30f;
        for (int k = 0; k < N; k++) m = fmaxf(m, sh_s[k]);
        float sum = 0.f;
        for (int k = 0; k < N; k++) {
            float e = __builtin_amdgcn_exp2f((sh_s[k] - m) * 1.4426950408889634f);
            sh_p[k] = e; sum += e;
        }
        float inv = 1.f / sum, sagg = 0.f;
        for (int k = 0; k < N; k++) { sh_p[k] *= inv; sagg += sh_p[k] * sh_s[k]; }
        cs[b * NCELLS + cell] = sagg;
    }
    __syncthreads();

    float ha0 = 0, ha1 = 0, ca0 = 0, ca1 = 0;
    const int d = t * 2;
    if (d < DD) {
        const float bh0 = b_h[d], bh1 = b_h[d + 1], bc0 = b_c[d], bc1 = b_c[d + 1];
        const uint16_t* lpb = LP + (size_t)(b * NCELLS) * 800 + 2 * d;
        const uint16_t* rpb = RP + (size_t)(b * NCELLS) * 800 + 2 * d;
        int lcell = i;
        int rcell = offs_of(level - 1) + i + 1;
        uint2 lv = *(const uint2*)(lpb + (size_t)lcell * 800);
        uint2 rv = *(const uint2*)(rpb + (size_t)rcell * 800);
        for (int k = 0; k < N; k++) {
            uint2 lc = lv, rc = rv;
            if (k + 1 < N) {
                int ln = offs_of(k + 1) + i;
                int rn = offs_of(level - k - 2) + i + k + 2;
                lv = *(const uint2*)(lpb + (size_t)ln * 800);
                rv = *(const uint2*)(rpb + (size_t)rn * 800);
            }
            float p = sh_p[k];
            ha0 += p * tanh_fast(asf(lc.x << 16) + asf(rc.x << 16) + bh0);
            ca0 += p * tanh_fast(asf(lc.x & 0xffff0000u) + asf(rc.x & 0xffff0000u) + bc0);
            ha1 += p * tanh_fast(asf(lc.y << 16) + asf(rc.y << 16) + bh1);
            ca1 += p * tanh_fast(asf(lc.y & 0xffff0000u) + asf(rc.y & 0xffff0000u) + bc1);
        }
    }
    float nh = ha0 * ha0 + ha1 * ha1, nc = ca0 * ca0 + ca1 * ca1;
    block_reduce2(nh, nc, sred);
    float rh = 1.f / fmaxf(sqrtf(nh), 1e-8f);
    float rc = 1.f / fmaxf(sqrtf(nc), 1e-8f);
    if (d < DD) {
        float h0 = ha0 * rh, h1 = ha1 * rh, c0 = ca0 * rc, c1 = ca1 * rc;
        size_t ho = (size_t)(b * NCELLS + cell) * DD + d;
        Hchart[ho] = h0; Hchart[ho + 1] = h1;
        *(uint32_t*)(HB + ho) = (uint32_t)f2bf(h0) | ((uint32_t)f2bf(h1) << 16);
        *(uint32_t*)(CB + (size_t)(b * 32 + i) * DD + d) =
            (uint32_t)f2bf(c0) | ((uint32_t)f2bf(c1) << 16);
    }
}

// Standalone per-level cell kernel (fallback path; R11 mapping w/ XCD swizzle)
__global__ __launch_bounds__(256)
void level_k(float* __restrict__ Hchart, uint16_t* __restrict__ HB,
             uint16_t* __restrict__ CB, float* __restrict__ cs,
             const uint16_t* __restrict__ LP, const uint16_t* __restrict__ RP,
             const uint16_t* __restrict__ G,
             const float* __restrict__ b_h, const float* __restrict__ b_c, int level) {
    __shared__ float sh_s[32], sh_p[32], sred[8];
    const int L = TT - level;
    const int blk = (blockIdx.x & 7) * (gridDim.x >> 3) + (blockIdx.x >> 3);
    level_cell(Hchart, HB, CB, cs, LP, RP, G, b_h, b_c, level,
               blk / L, blk % L, sh_s, sh_p, sred);
}

// ---------------- persistent group-pipeline kernel ----------------
struct GArgs {
    float* Hchart; uint16_t* HB; uint16_t* CB; float* CS;
    uint16_t* LP; uint16_t* RP; uint16_t* G; const uint16_t* WT;
    const float* b_h; const float* b_c; uint32_t* CNT;
};

__global__ __launch_bounds__(256)
void diora_groups_k(GArgs A) {
    __shared__ short AsH[128][40], AsC[128][40], WsH[80][40], WsC[80][40];
    __shared__ float sh_s[32], sh_p[32], sred[8];
    const int g = blockIdx.x & 7;        // group = XCD-affine
    const int jj = blockIdx.x >> 3;      // 0..63 within group
    const int b_base = g * 16;
    uint32_t* cnt = A.CNT + g * 62;
    int seq = 0;

    int off = TT;
    for (int lv = 1; lv < TT; ++lv) {
        const int L = TT - lv;
        // Cell phase: 16*L cells of this group's b-range, grid-strided.
        for (int ci = jj; ci < 16 * L; ci += 64) {
            int bl = ci / L, i = ci - bl * L;
            level_cell(A.Hchart, A.HB, A.CB, A.CS, A.LP, A.RP, A.G,
                       A.b_h, A.b_c, lv, b_base + bl, i, sh_s, sh_p, sred);
        }
        if (lv < TT - 1) {
            group_barrier(cnt + seq); seq++;   // cells visible -> transform
            const int Mtot = 16 * L;
            const int Mt = (Mtot + 127) >> 7;
            const int ntiles = 15 * Mt;
            for (int tile = jj; tile < ntiles; tile += 64) {
                int tx = tile % 15, ty = tile / 15;
                tpgemm_tile(A.HB, A.CB, A.WT, A.LP, A.RP, A.G,
                            L, off, b_base, tx % 5, tx / 5, ty * 128, Mtot,
                            AsH, AsC, WsH, WsC);
            }
            group_barrier(cnt + seq); seq++;   // transforms visible -> next level
        }
        off += L;
    }
}

extern "C" void kernel_launch(void* const* d_in, const int* in_sizes, int n_in,
                              void* d_out, int out_size, void* d_ws, size_t ws_size,
                              hipStream_t stream) {
    const float* x        = (const float*)d_in[0];
    const float* w_leaf_h = (const float*)d_in[1];
    const float* b_leaf_h = (const float*)d_in[2];
    const float* w_leaf_c = (const float*)d_in[3];
    const float* b_leaf_c = (const float*)d_in[4];
    const float* u_lh     = (const float*)d_in[5];
    const float* u_rh     = (const float*)d_in[6];
    const float* b_h      = (const float*)d_in[7];
    const float* u_lc     = (const float*)d_in[8];
    const float* u_rc     = (const float*)d_in[9];
    const float* b_c      = (const float*)d_in[10];
    const float* w_score  = (const float*)d_in[11];
    float* Hchart = (float*)d_out;

    const size_t PL = (size_t)BB * NCELLS * DD;
    char* p = (char*)d_ws;
    uint16_t* LP = (uint16_t*)p; p += 2 * PL * sizeof(uint16_t);        // 108.2 MB
    uint16_t* RP = (uint16_t*)p; p += 2 * PL * sizeof(uint16_t);        // 108.2 MB
    uint16_t* G  = (uint16_t*)p; p += PL * sizeof(uint16_t);            // 54.1 MB
    uint16_t* HB = (uint16_t*)p; p += PL * sizeof(uint16_t) + 64;       // 54.1 MB (+pad)
    uint16_t* CB = (uint16_t*)p; p += (size_t)BB * 32 * DD * sizeof(uint16_t) + 64;
    float* CS    = (float*)p;    p += (size_t)BB * NCELLS * sizeof(float);
    uint16_t* WT = (uint16_t*)p; p += (size_t)NW * KP * sizeof(uint16_t);
    uint32_t* CNT= (uint32_t*)p; p += 512 * sizeof(uint32_t);
    // Aliases (dead before their hosts' first writes):
    float* PRE    = (float*)LP;            // dead before first LP write
    uint16_t* WLT = RP;                    // dead before first RP write
    uint16_t* XB  = RP + (size_t)800 * KP; // dead before first RP write

    {
        int total = NW * KP + 800 * KP + 4096 * KP + 512;
        pack_k<<<(total + 255) / 256, 256, 0, stream>>>(u_lh, u_rh, w_score, u_lc, u_rc,
                                                        w_leaf_h, w_leaf_c, x, WT, WLT, XB, CNT);
    }
    // Leaf pre-activations via MFMA: XB(4096x416) @ WLT^T(800x416) -> PRE fp32
    tgemm_k<<<dim3(10, 16), 256, 0, stream>>>(XB, WLT, PRE);
    leaf_norm_k<<<BB * TT, 256, 0, stream>>>(PRE, b_leaf_h, b_leaf_c, Hchart, HB, CB, CS);
    // Leaf transforms into interleaved planes (paired kernel; M = 4096 rows)
    tpgemm_k<<<dim3(15, 32), 256, 0, stream>>>(HB, CB, WT, LP, RP, G, 32, 0);

    // Levels 1..31: 8 independent group-pipelines, 512 blocks, coop launch.
    int occ = 0;
    hipError_t qerr = hipOccupancyMaxActiveBlocksPerMultiprocessor(
        &occ, (const void*)diora_groups_k, 256, 0);
    bool coop_ok = (qerr == hipSuccess) && (occ * 256 >= 512);
    if (coop_ok) {
        GArgs ga{Hchart, HB, CB, CS, LP, RP, G, WT, b_h, b_c, CNT};
        void* kargs[] = {&ga};
        hipError_t lerr = hipLaunchCooperativeKernel((void*)diora_groups_k, dim3(512),
                                                     dim3(256), kargs, 0, stream);
        if (lerr != hipSuccess) coop_ok = false;
    }
    if (!coop_ok) {
        // Fallback: R11-verified per-level multi-launch
        int off = TT;
        for (int level = 1; level < TT; ++level) {
            int L = TT - level;
            level_k<<<BB * L, 256, 0, stream>>>(Hchart, HB, CB, CS, LP, RP, G,
                                                b_h, b_c, level);
            if (level < TT - 1) {
                tpgemm_k<<<dim3(15, L), 256, 0, stream>>>(HB, CB, WT, LP, RP, G, L, off);
            }
            off += L;
        }
    }
}

// Round 13
// 1645.730 us; speedup vs baseline: 1.0109x; 1.0109x over previous
//
#include <hip/hip_runtime.h>
#include <hip/hip_bf16.h>
#include <stdint.h>

// DIORA inside pass. B=128, T=32, D=400, ncells=528.
// Per-cell transform caching via bf16 MFMA GEMM into interleaved planes:
//   LP[cell][2j+0]=a_j (h@u_lh), LP[cell][2j+1]=e_j (c@u_lc)
//   RP[cell][2j+0]=b2_j (h@u_rh), RP[cell][2j+1]=f_j (c@u_rc)
//   G [cell][j]   =g_j (h@w_score)
// Structure: per-level multi-launch (61 dependent launches). Measured dead
// ends: coop grid.sync ~140us/sync (R7); 64-block agent-scope barrier
// ~95us/barrier (R12) — agent release/acquire = L2 wb/inv on 8-XCD gfx950.
// Launch boundaries are the cheapest sync on this chip.
// Hchart (d_out) is write-once-never-read -> nontemporal stores keep it from
// evicting the re-read-hot planes (LP/RP/G/HB) in L2/L3.

#define BB 128
#define TT 32
#define DD 400
#define NCELLS 528
#define NW 2000   // 5 weight blocks x 400 output cols
#define KP 416    // K padded to 13*32

typedef __attribute__((ext_vector_type(8))) short s8v;
typedef __attribute__((ext_vector_type(4))) float f32x4;
typedef __attribute__((ext_vector_type(2))) float f32x2;

__device__ __forceinline__ int offs_of(int v) { return v * TT - (v * (v - 1)) / 2; }

__device__ __forceinline__ float asf(uint32_t bits) {
    union { uint32_t i; float f; } v; v.i = bits; return v.f;
}
__device__ __forceinline__ uint16_t f2bf(float f) {
    union { float f; uint32_t i; } v; v.f = f;
    uint32_t x = v.i;
    return (uint16_t)((x + 0x7fffu + ((x >> 16) & 1u)) >> 16);  // RNE
}
// Fast tanh: 1 - 2/(exp2(2*log2e*x)+1). ~1e-6 abs error.
__device__ __forceinline__ float tanh_fast(float x) {
    float e = __builtin_amdgcn_exp2f(x * 2.8853900817779268f);
    return 1.f - 2.f * __builtin_amdgcn_rcpf(e + 1.f);
}

__device__ __forceinline__ void block_reduce2(float& a, float& b, float* sred) {
#pragma unroll
    for (int o = 32; o > 0; o >>= 1) { a += __shfl_down(a, o); b += __shfl_down(b, o); }
    int lane = threadIdx.x & 63, w = threadIdx.x >> 6;
    if (lane == 0) { sred[w] = a; sred[4 + w] = b; }
    __syncthreads();
    a = sred[0] + sred[1] + sred[2] + sred[3];
    b = sred[4] + sred[5] + sred[6] + sred[7];
    __syncthreads();
}

// ---------------- pack ----------------
// WT bf16 [2000][416] = transposed [u_lh|u_rh|w_score|u_lc|u_rc] (k>=400 zero);
// WLT bf16 [800][416] = transposed [w_leaf_h|w_leaf_c];
// XB bf16 [4096][416] = x rows, k-padded with zeros.
__global__ void pack_k(const float* __restrict__ u_lh, const float* __restrict__ u_rh,
                       const float* __restrict__ w_score, const float* __restrict__ u_lc,
                       const float* __restrict__ u_rc, const float* __restrict__ w_leaf_h,
                       const float* __restrict__ w_leaf_c, const float* __restrict__ x,
                       uint16_t* __restrict__ WT, uint16_t* __restrict__ WLT,
                       uint16_t* __restrict__ XB) {
    int idx = blockIdx.x * blockDim.x + threadIdx.x;
    const int nWT = NW * KP, nWLT = 800 * KP, nXB = 4096 * KP;
    if (idx < nWT) {
        int n = idx / KP, k = idx - n * KP;
        float v = 0.f;
        if (k < DD) {
            const float* src = (n < 400) ? u_lh : (n < 800) ? u_rh : (n < 1200) ? w_score
                               : (n < 1600) ? u_lc : u_rc;
            v = src[k * DD + (n % 400)];
        }
        WT[idx] = f2bf(v);
    } else if (idx < nWT + nWLT) {
        int q = idx - nWT; int n = q / KP, k = q - n * KP;
        float v = 0.f;
        if (k < DD) v = (n < 400) ? w_leaf_h[k * DD + n] : w_leaf_c[k * DD + (n - 400)];
        WLT[q] = f2bf(v);
    } else if (idx < nWT + nWLT + nXB) {
        int q = idx - nWT - nWLT; int r = q / KP, k = q - r * KP;
        XB[q] = f2bf(k < DD ? x[(size_t)r * DD + k] : 0.f);
    }
}

// ---------------- leaf pre-activation GEMM (verified; LDS-staged) ----------
__global__ __launch_bounds__(256)
void tgemm_k(const uint16_t* __restrict__ XB, const uint16_t* __restrict__ WLT,
             float* __restrict__ PREout) {
    __shared__ short As[256][40];
    __shared__ short Ws[80][40];
    const int t = threadIdx.x, lane = t & 63, w = t >> 6;
    const int n0 = blockIdx.x * 80;
    const int tile_m = blockIdx.y * 256;

    const int arow_l = t >> 2, asub = t & 3;
    const uint16_t* aptr[4];
#pragma unroll
    for (int p = 0; p < 4; p++) {
        int gr = tile_m + arow_l + 64 * p;
        aptr[p] = XB + (size_t)gr * KP + asub * 8;
    }
    const uint16_t* wptr0 = WLT + (size_t)(n0 + (t >> 2)) * KP + (t & 3) * 8;
    const uint16_t* wptr1 = WLT + (size_t)(n0 + 64 + (t >> 2)) * KP + (t & 3) * 8;

    const int frow = lane & 15, kcol = (lane >> 4) * 8;
    f32x4 acc[4][5];
#pragma unroll
    for (int mi = 0; mi < 4; mi++)
#pragma unroll
        for (int ni = 0; ni < 5; ni++) acc[mi][ni] = (f32x4)(0.f);

    for (int k0 = 0; k0 < KP; k0 += 32) {
        s8v av[4];
#pragma unroll
        for (int p = 0; p < 4; p++) av[p] = *(const s8v*)(aptr[p] + k0);
        s8v wv0 = *(const s8v*)(wptr0 + k0);
        s8v wv1;
        if (t < 64) wv1 = *(const s8v*)(wptr1 + k0);
        __syncthreads();
#pragma unroll
        for (int p = 0; p < 4; p++) *(s8v*)&As[arow_l + 64 * p][asub * 8] = av[p];
        *(s8v*)&Ws[t >> 2][(t & 3) * 8] = wv0;
        if (t < 64) *(s8v*)&Ws[64 + (t >> 2)][(t & 3) * 8] = wv1;
        __syncthreads();
        s8v a[4];
#pragma unroll
        for (int mi = 0; mi < 4; mi++)
            a[mi] = *(const s8v*)&As[64 * w + 16 * mi + frow][kcol];
#pragma unroll
        for (int ni = 0; ni < 5; ni++) {
            s8v bv = *(const s8v*)&Ws[16 * ni + frow][kcol];
#pragma unroll
            for (int mi = 0; mi < 4; mi++)
                acc[mi][ni] = __builtin_amdgcn_mfma_f32_16x16x32_bf16(a[mi], bv, acc[mi][ni], 0, 0, 0);
        }
    }
#pragma unroll
    for (int mi = 0; mi < 4; mi++) {
        int rbase = tile_m + 64 * w + 16 * mi + 4 * (lane >> 4);
#pragma unroll
        for (int i = 0; i < 4; i++) {
            int gr = rbase + i;
            float* o = PREout + (size_t)gr * 800 + n0 + frow;
#pragma unroll
            for (int ni = 0; ni < 5; ni++) o[16 * ni] = acc[mi][ni][i];
        }
    }
}

// ---------------- paired transform GEMM (R8-verified, LDS-staged) ----------
// Block kinds (blockIdx.x / 5): 0 = LP pair (u_lh + u_lc), 1 = RP pair
// (u_rh + u_rc), 2 = G (w_score only). n0 = (blockIdx.x % 5) * 80.
// 128-row m-tile (M = 128*Lcur, multiple of 128). Paired kinds compute h-side
// (A = HB cell rows) AND c-side (A = CB rows); dense 4B store a|e<<16.
__global__ __launch_bounds__(256)
void tpgemm_k(const uint16_t* __restrict__ HB, const uint16_t* __restrict__ CB,
              const uint16_t* __restrict__ WT,
              uint16_t* __restrict__ LP, uint16_t* __restrict__ RP,
              uint16_t* __restrict__ G, int Lcur, int cellbase) {
    __shared__ short AsH[128][40];
    __shared__ short AsC[128][40];
    __shared__ short WsH[80][40];
    __shared__ short WsC[80][40];
    const int t = threadIdx.x, lane = t & 63, w = t >> 6;
    const int nch = blockIdx.x % 5, kind = blockIdx.x / 5;
    const int n0 = nch * 80;
    const int tile_m = blockIdx.y * 128;
    const bool doC = (kind != 2);

    const int wh0 = (kind == 0) ? n0 : (kind == 1) ? 400 + n0 : 800 + n0;
    const int wc0 = (kind == 0) ? 1200 + n0 : 1600 + n0;  // unused for kind==2

    const int arow_l = t >> 2, asub = t & 3;
    const uint16_t *aptrH[2], *aptrC[2];
#pragma unroll
    for (int p = 0; p < 2; p++) {
        int gr = tile_m + arow_l + 64 * p;
        int rb = gr / Lcur, ri = gr - rb * Lcur;
        aptrH[p] = HB + (size_t)(rb * NCELLS + cellbase + ri) * DD + asub * 8;
        aptrC[p] = CB + (size_t)(rb * 32 + ri) * DD + asub * 8;
    }
    const uint16_t* wptrH0 = WT + (size_t)(wh0 + (t >> 2)) * KP + (t & 3) * 8;
    const uint16_t* wptrH1 = WT + (size_t)(wh0 + 64 + (t >> 2)) * KP + (t & 3) * 8;
    const uint16_t* wptrC0 = WT + (size_t)(wc0 + (t >> 2)) * KP + (t & 3) * 8;
    const uint16_t* wptrC1 = WT + (size_t)(wc0 + 64 + (t >> 2)) * KP + (t & 3) * 8;

    const int frow = lane & 15, kcol = (lane >> 4) * 8;
    f32x4 accH[2][5], accC[2][5];
#pragma unroll
    for (int mi = 0; mi < 2; mi++)
#pragma unroll
        for (int ni = 0; ni < 5; ni++) { accH[mi][ni] = (f32x4)(0.f); accC[mi][ni] = (f32x4)(0.f); }

    for (int k0 = 0; k0 < KP; k0 += 32) {
        s8v avH0 = *(const s8v*)(aptrH[0] + k0);
        s8v avH1 = *(const s8v*)(aptrH[1] + k0);
        s8v wvH0 = *(const s8v*)(wptrH0 + k0);
        s8v wvH1;
        if (t < 64) wvH1 = *(const s8v*)(wptrH1 + k0);
        s8v avC0, avC1, wvC0, wvC1;
        if (doC) {
            avC0 = *(const s8v*)(aptrC[0] + k0);
            avC1 = *(const s8v*)(aptrC[1] + k0);
            wvC0 = *(const s8v*)(wptrC0 + k0);
            if (t < 64) wvC1 = *(const s8v*)(wptrC1 + k0);
        }
        __syncthreads();
        *(s8v*)&AsH[arow_l][asub * 8] = avH0;
        *(s8v*)&AsH[arow_l + 64][asub * 8] = avH1;
        *(s8v*)&WsH[t >> 2][(t & 3) * 8] = wvH0;
        if (t < 64) *(s8v*)&WsH[64 + (t >> 2)][(t & 3) * 8] = wvH1;
        if (doC) {
            *(s8v*)&AsC[arow_l][asub * 8] = avC0;
            *(s8v*)&AsC[arow_l + 64][asub * 8] = avC1;
            *(s8v*)&WsC[t >> 2][(t & 3) * 8] = wvC0;
            if (t < 64) *(s8v*)&WsC[64 + (t >> 2)][(t & 3) * 8] = wvC1;
        }
        __syncthreads();
        s8v aH0 = *(const s8v*)&AsH[32 * w + frow][kcol];
        s8v aH1 = *(const s8v*)&AsH[32 * w + 16 + frow][kcol];
        s8v aC0, aC1;
        if (doC) {
            aC0 = *(const s8v*)&AsC[32 * w + frow][kcol];
            aC1 = *(const s8v*)&AsC[32 * w + 16 + frow][kcol];
        }
#pragma unroll
        for (int ni = 0; ni < 5; ni++) {
            s8v bvH = *(const s8v*)&WsH[16 * ni + frow][kcol];
            accH[0][ni] = __builtin_amdgcn_mfma_f32_16x16x32_bf16(aH0, bvH, accH[0][ni], 0, 0, 0);
            accH[1][ni] = __builtin_amdgcn_mfma_f32_16x16x32_bf16(aH1, bvH, accH[1][ni], 0, 0, 0);
            if (doC) {
                s8v bvC = *(const s8v*)&WsC[16 * ni + frow][kcol];
                accC[0][ni] = __builtin_amdgcn_mfma_f32_16x16x32_bf16(aC0, bvC, accC[0][ni], 0, 0, 0);
                accC[1][ni] = __builtin_amdgcn_mfma_f32_16x16x32_bf16(aC1, bvC, accC[1][ni], 0, 0, 0);
            }
        }
    }

    if (kind == 2) {
#pragma unroll
        for (int mi = 0; mi < 2; mi++) {
            int rbase = tile_m + 32 * w + 16 * mi + 4 * (lane >> 4);
#pragma unroll
            for (int i = 0; i < 4; i++) {
                int gr = rbase + i;
                int rb = gr / Lcur, ri = gr - rb * Lcur;
                size_t row = (size_t)(rb * NCELLS + cellbase + ri);
                uint16_t* o = G + row * 400 + n0 + frow;
#pragma unroll
                for (int ni = 0; ni < 5; ni++) o[16 * ni] = f2bf(accH[mi][ni][i]);
            }
        }
    } else {
        uint16_t* tb = (kind == 0) ? LP : RP;
#pragma unroll
        for (int mi = 0; mi < 2; mi++) {
            int rbase = tile_m + 32 * w + 16 * mi + 4 * (lane >> 4);
#pragma unroll
            for (int i = 0; i < 4; i++) {
                int gr = rbase + i;
                int rb = gr / Lcur, ri = gr - rb * Lcur;
                size_t row = (size_t)(rb * NCELLS + cellbase + ri);
                uint32_t* o = (uint32_t*)(tb + row * 800) + n0 + frow;
#pragma unroll
                for (int ni = 0; ni < 5; ni++)
                    o[16 * ni] = (uint32_t)f2bf(accH[mi][ni][i])
                               | ((uint32_t)f2bf(accC[mi][ni][i]) << 16);
            }
        }
    }
}

// ---------------- leaf epilogue ----------------
__global__ __launch_bounds__(256)
void leaf_norm_k(const float* __restrict__ PRE, const float* __restrict__ blh,
                 const float* __restrict__ blc, float* __restrict__ Hchart,
                 uint16_t* __restrict__ HB, uint16_t* __restrict__ CB,
                 float* __restrict__ cs) {
    const int r = blockIdx.x;  // b*32 + t
    const int b = r >> 5, tt = r & 31;
    const int t = threadIdx.x;
    const int d = t * 2;
    float th0 = 0, th1 = 0, tc0 = 0, tc1 = 0;
    if (d < DD) {
        const float* p = PRE + (size_t)r * 800;
        th0 = tanh_fast(p[d] + blh[d]);
        th1 = tanh_fast(p[d + 1] + blh[d + 1]);
        tc0 = tanh_fast(p[400 + d] + blc[d]);
        tc1 = tanh_fast(p[400 + d + 1] + blc[d + 1]);
    }
    __shared__ float sred[8];
    float nh = th0 * th0 + th1 * th1, nc = tc0 * tc0 + tc1 * tc1;
    block_reduce2(nh, nc, sred);
    float rh = 1.f / fmaxf(sqrtf(nh), 1e-8f);
    float rc = 1.f / fmaxf(sqrtf(nc), 1e-8f);
    if (d < DD) {
        size_t ho = (size_t)(b * NCELLS + tt) * DD + d;
        float h0 = th0 * rh, h1 = th1 * rh, c0 = tc0 * rc, c1 = tc1 * rc;
        f32x2 hv; hv[0] = h0; hv[1] = h1;
        __builtin_nontemporal_store(hv, (f32x2*)(Hchart + ho));  // write-once output
        *(uint32_t*)(HB + ho) = (uint32_t)f2bf(h0) | ((uint32_t)f2bf(h1) << 16);
        *(uint32_t*)(CB + (size_t)(b * 32 + tt) * DD + d) =
            (uint32_t)f2bf(c0) | ((uint32_t)f2bf(c1) << 16);
    }
    if (t == 0) cs[b * NCELLS + tt] = 0.f;
}

// ---------------- per-level cell kernel ----------------
// XCD swizzle: gridDim.x = 128*L is always a multiple of 8 -> bijective remap
// blk = (bid&7)*(nwg>>3) + (bid>>3); each XCD gets a contiguous (b,i) range.
__global__ __launch_bounds__(256)
void level_k(float* __restrict__ Hchart, uint16_t* __restrict__ HB,
             uint16_t* __restrict__ CB, float* __restrict__ cs,
             const uint16_t* __restrict__ LP, const uint16_t* __restrict__ RP,
             const uint16_t* __restrict__ G,
             const float* __restrict__ b_h, const float* __restrict__ b_c, int level) {
    const int L = TT - level, N = level;
    const int blk = (blockIdx.x & 7) * (gridDim.x >> 3) + (blockIdx.x >> 3);
    const int b = blk / L, i = blk - b * L;
    const int cell = offs_of(level) + i;
    const int t = threadIdx.x, lane = t & 63, w = t >> 6;
    __shared__ float sh_s[32], sh_p[32];
    __shared__ float sred[8];

    // Phase 1: scores s_k = g[lcell] . h[rcell] (+ child scores)
    for (int k = w; k < N; k += 4) {
        int lcell = offs_of(k) + i;
        int rcell = offs_of(level - k - 1) + i + k + 1;
        const uint32_t* g = (const uint32_t*)(G + (size_t)(b * NCELLS + lcell) * DD);
        const uint32_t* hr = (const uint32_t*)(HB + (size_t)(b * NCELLS + rcell) * DD);
        float s = 0.f;
        for (int d2 = lane; d2 < 200; d2 += 64) {
            uint32_t gv = g[d2], hv = hr[d2];
            s += asf(gv << 16) * asf(hv << 16)
               + asf(gv & 0xffff0000u) * asf(hv & 0xffff0000u);
        }
#pragma unroll
        for (int o = 32; o > 0; o >>= 1) s += __shfl_down(s, o);
        if (lane == 0) sh_s[k] = s + cs[b * NCELLS + lcell] + cs[b * NCELLS + rcell];
    }
    __syncthreads();

    // Phase 2: softmax over N (tiny)
    if (t == 0) {
        float m = -1e30f;
        for (int k = 0; k < N; k++) m = fmaxf(m, sh_s[k]);
        float sum = 0.f;
        for (int k = 0; k < N; k++) {
            float e = __builtin_amdgcn_exp2f((sh_s[k] - m) * 1.4426950408889634f);
            sh_p[k] = e; sum += e;
        }
        float inv = 1.f / sum, sagg = 0.f;
        for (int k = 0; k < N; k++) { sh_p[k] *= inv; sagg += sh_p[k] * sh_s[k]; }
        cs[b * NCELLS + cell] = sagg;
    }
    __syncthreads();

    // Phase 3: aggregate; thread owns dims (2t, 2t+1); 8B loads from LP/RP,
    // 2-deep software pipeline (prefetch next pair before consuming current).
    float ha0 = 0, ha1 = 0, ca0 = 0, ca1 = 0;
    const int d = t * 2;
    if (d < DD) {
        const float bh0 = b_h[d], bh1 = b_h[d + 1], bc0 = b_c[d], bc1 = b_c[d + 1];
        const uint16_t* lpb = LP + (size_t)(b * NCELLS) * 800 + 2 * d;
        const uint16_t* rpb = RP + (size_t)(b * NCELLS) * 800 + 2 * d;
        int lcell = i;                             // offs_of(0) + i
        int rcell = offs_of(level - 1) + i + 1;
        uint2 lv = *(const uint2*)(lpb + (size_t)lcell * 800);
        uint2 rv = *(const uint2*)(rpb + (size_t)rcell * 800);
        for (int k = 0; k < N; k++) {
            uint2 lc = lv, rc = rv;
            if (k + 1 < N) {
                int ln = offs_of(k + 1) + i;
                int rn = offs_of(level - k - 2) + i + k + 2;
                lv = *(const uint2*)(lpb + (size_t)ln * 800);
                rv = *(const uint2*)(rpb + (size_t)rn * 800);
            }
            float p = sh_p[k];
            ha0 += p * tanh_fast(asf(lc.x << 16) + asf(rc.x << 16) + bh0);
            ca0 += p * tanh_fast(asf(lc.x & 0xffff0000u) + asf(rc.x & 0xffff0000u) + bc0);
            ha1 += p * tanh_fast(asf(lc.y << 16) + asf(rc.y << 16) + bh1);
            ca1 += p * tanh_fast(asf(lc.y & 0xffff0000u) + asf(rc.y & 0xffff0000u) + bc1);
        }
    }
    float nh = ha0 * ha0 + ha1 * ha1, nc = ca0 * ca0 + ca1 * ca1;
    block_reduce2(nh, nc, sred);
    float rh = 1.f / fmaxf(sqrtf(nh), 1e-8f);
    float rc = 1.f / fmaxf(sqrtf(nc), 1e-8f);
    if (d < DD) {
        float h0 = ha0 * rh, h1 = ha1 * rh, c0 = ca0 * rc, c1 = ca1 * rc;
        size_t ho = (size_t)(b * NCELLS + cell) * DD + d;
        f32x2 hv2; hv2[0] = h0; hv2[1] = h1;
        __builtin_nontemporal_store(hv2, (f32x2*)(Hchart + ho));  // write-once output
        *(uint32_t*)(HB + ho) = (uint32_t)f2bf(h0) | ((uint32_t)f2bf(h1) << 16);
        *(uint32_t*)(CB + (size_t)(b * 32 + i) * DD + d) =
            (uint32_t)f2bf(c0) | ((uint32_t)f2bf(c1) << 16);
    }
}

extern "C" void kernel_launch(void* const* d_in, const int* in_sizes, int n_in,
                              void* d_out, int out_size, void* d_ws, size_t ws_size,
                              hipStream_t stream) {
    const float* x        = (const float*)d_in[0];
    const float* w_leaf_h = (const float*)d_in[1];
    const float* b_leaf_h = (const float*)d_in[2];
    const float* w_leaf_c = (const float*)d_in[3];
    const float* b_leaf_c = (const float*)d_in[4];
    const float* u_lh     = (const float*)d_in[5];
    const float* u_rh     = (const float*)d_in[6];
    const float* b_h      = (const float*)d_in[7];
    const float* u_lc     = (const float*)d_in[8];
    const float* u_rc     = (const float*)d_in[9];
    const float* b_c      = (const float*)d_in[10];
    const float* w_score  = (const float*)d_in[11];
    float* Hchart = (float*)d_out;

    const size_t PL = (size_t)BB * NCELLS * DD;
    char* p = (char*)d_ws;
    uint16_t* LP = (uint16_t*)p; p += 2 * PL * sizeof(uint16_t);        // 108.2 MB
    uint16_t* RP = (uint16_t*)p; p += 2 * PL * sizeof(uint16_t);        // 108.2 MB
    uint16_t* G  = (uint16_t*)p; p += PL * sizeof(uint16_t);            // 54.1 MB
    uint16_t* HB = (uint16_t*)p; p += PL * sizeof(uint16_t) + 64;       // 54.1 MB (+pad)
    uint16_t* CB = (uint16_t*)p; p += (size_t)BB * 32 * DD * sizeof(uint16_t) + 64;
    float* CS    = (float*)p;    p += (size_t)BB * NCELLS * sizeof(float);
    uint16_t* WT = (uint16_t*)p; p += (size_t)NW * KP * sizeof(uint16_t);
    // Aliases (dead before their hosts' first writes):
    float* PRE    = (float*)LP;            // dead before first LP write
    uint16_t* WLT = RP;                    // dead before first RP write
    uint16_t* XB  = RP + (size_t)800 * KP; // dead before first RP write

    {
        int total = NW * KP + 800 * KP + 4096 * KP;
        pack_k<<<(total + 255) / 256, 256, 0, stream>>>(u_lh, u_rh, w_score, u_lc, u_rc,
                                                        w_leaf_h, w_leaf_c, x, WT, WLT, XB);
    }
    // Leaf pre-activations via MFMA: XB(4096x416) @ WLT^T(800x416) -> PRE fp32
    tgemm_k<<<dim3(10, 16), 256, 0, stream>>>(XB, WLT, PRE);
    leaf_norm_k<<<BB * TT, 256, 0, stream>>>(PRE, b_leaf_h, b_leaf_c, Hchart, HB, CB, CS);
    // Leaf transforms into interleaved planes (paired kernel; M = 4096 rows)
    tpgemm_k<<<dim3(15, 32), 256, 0, stream>>>(HB, CB, WT, LP, RP, G, 32, 0);

    int off = TT;
    for (int level = 1; level < TT; ++level) {
        int L = TT - level;
        level_k<<<BB * L, 256, 0, stream>>>(Hchart, HB, CB, CS, LP, RP, G, b_h, b_c, level);
        if (level < TT - 1) {
            tpgemm_k<<<dim3(15, L), 256, 0, stream>>>(HB, CB, WT, LP, RP, G, L, off);
        }
        off += L;
    }
}